// Round 2
// baseline (1122.828 us; speedup 1.0000x reference)
//
#include <hip/hip_runtime.h>
#include <hip/hip_bf16.h>

// GCN via bucketed COO aggregation. Round-5 changes vs round-4:
//  - NO global atomics anywhere: rocprof showed each global atomic is a
//    memory-side op (~32B HBM write, ~24G/s): hist_kernel was 131us at 0.6%
//    VALUBusy. All binning/ranking now uses LDS atomics.
//  - full counting sort by dst replaced by grouping into 128-node buckets
//    (782 buckets): p0 LDS-histogram -> 2 small scans -> p1 scatter with
//    LDS cursors. (dst&127) packed into src's high bits (8B/edge total).
//  - dinv + both agg layers are per-bucket kernels: 128x16 accumulator in
//    LDS (ds_add_f32), edges streamed coalesced, feat gathers LLC-resident.
//    Replaces CSR pull (sorted/row_start/rank all gone), as is the memset.

#define D_IN 512
#define D_HID 16
#define D_OUT 64
#define BDIM 128     // nodes per bucket
#define BSHIFT 7
#define NBLK0 512    // edge-chunk blocks for p0/p1 (p_scan1 assumes 512 = 2*256)

// ---------------- pass 0: per-chunk bucket histogram (LDS atomics) --------
__global__ __launch_bounds__(256) void p0_count(const int* __restrict__ dst,
                                                int* __restrict__ bcnt,
                                                int NBUCK, int E, int chunk) {
    extern __shared__ int hist[];  // NBUCK ints
    int k = blockIdx.x;
    for (int i = threadIdx.x; i < NBUCK; i += 256) hist[i] = 0;
    __syncthreads();
    int beg = k * chunk, end = min(beg + chunk, E);
    for (int e = beg + threadIdx.x; e < end; e += 256)
        atomicAdd(&hist[dst[e] >> BSHIFT], 1);
    __syncthreads();
    for (int i = threadIdx.x; i < NBUCK; i += 256)
        bcnt[(size_t)k * NBUCK + i] = hist[i];  // row-major by chunk: coalesced
}

// ------- scan 1: per bucket, exclusive scan over the NBLK0 chunks ---------
__global__ __launch_bounds__(256) void p_scan1(int* __restrict__ bcnt,
                                               int* __restrict__ btot, int NBUCK) {
    __shared__ int s[256];
    int b = blockIdx.x, t = threadIdx.x;
    int v0 = bcnt[(size_t)(2 * t) * NBUCK + b];
    int v1 = bcnt[(size_t)(2 * t + 1) * NBUCK + b];
    int pair = v0 + v1;
    s[t] = pair;
    __syncthreads();
    for (int off = 1; off < 256; off <<= 1) {
        int v = (t >= off) ? s[t - off] : 0;
        __syncthreads();
        s[t] += v;
        __syncthreads();
    }
    int ex = s[t] - pair;
    bcnt[(size_t)(2 * t) * NBUCK + b] = ex;
    bcnt[(size_t)(2 * t + 1) * NBUCK + b] = ex + v0;
    if (t == 255) btot[b] = s[255];
}

// ------- scan 2: exclusive scan of bucket totals -> bbase[NBUCK+1] --------
__global__ __launch_bounds__(1024) void p_scan2(const int* __restrict__ btot,
                                                int* __restrict__ bbase,
                                                int NBUCK, int E) {
    __shared__ int s[1024];
    int t = threadIdx.x;
    int v = (t < NBUCK) ? btot[t] : 0;
    s[t] = v;
    __syncthreads();
    for (int off = 1; off < 1024; off <<= 1) {
        int u = (t >= off) ? s[t - off] : 0;
        __syncthreads();
        s[t] += u;
        __syncthreads();
    }
    if (t < NBUCK) bbase[t] = s[t] - v;
    if (t == 0) bbase[NBUCK] = E;
}

// ---------------- pass 1: scatter into bucket-grouped COO -----------------
// pos = bbase[b] + chunk-exclusive-prefix + LDS-cursor rank. Runs of ~8
// consecutive 8B records per (chunk,bucket) merge into full lines in L2.
__global__ __launch_bounds__(256) void p1_scatter(const int* __restrict__ src,
                                                  const int* __restrict__ dst,
                                                  const float* __restrict__ w,
                                                  const int* __restrict__ bcnt,
                                                  const int* __restrict__ bbase,
                                                  float2* __restrict__ tmp,
                                                  int NBUCK, int E, int chunk) {
    extern __shared__ int cur[];  // NBUCK ints
    int k = blockIdx.x;
    for (int i = threadIdx.x; i < NBUCK; i += 256)
        cur[i] = bbase[i] + bcnt[(size_t)k * NBUCK + i];
    __syncthreads();
    int beg = k * chunk, end = min(beg + chunk, E);
    for (int e = beg + threadIdx.x; e < end; e += 256) {
        int d = dst[e];
        int b = d >> BSHIFT;
        int pos = atomicAdd(&cur[b], 1);
        tmp[pos] = make_float2(__int_as_float(((d & (BDIM - 1)) << 24) | src[e]), w[e]);
    }
}

// ------------- dinv[n] = rsqrt(1 + sum_in w); one block per bucket --------
__global__ __launch_bounds__(256) void p2_dinv(const float2* __restrict__ tmp,
                                               const int* __restrict__ bbase,
                                               float* __restrict__ dinv,
                                               int NBUCK, int N) {
    __shared__ float deg[BDIM];
    int b = blockIdx.x;
    if (threadIdx.x < BDIM) deg[threadIdx.x] = 0.0f;
    __syncthreads();
    int beg = bbase[b], end = bbase[b + 1];
    for (int e = beg + threadIdx.x; e < end; e += 256) {
        float2 p = tmp[e];
        int dl = ((unsigned)__float_as_int(p.x)) >> 24;
        atomicAdd(&deg[dl], p.y);
    }
    __syncthreads();
    int node = (b << BSHIFT) + threadIdx.x;
    if (threadIdx.x < BDIM && node < N)
        dinv[node] = __frsqrt_rn(1.0f + deg[threadIdx.x]);
}

// ------------- aggregation: one block per bucket, LDS accumulator ---------
// lane j=tid&15 owns feature dim j; 16-lane groups each stream every-16th
// edge of the bucket. acc stride 17 to spread LDS banks.
template <int LAYER>
__global__ __launch_bounds__(256) void p3_agg(const float2* __restrict__ tmp,
                                              const int* __restrict__ bbase,
                                              const float* __restrict__ feat,
                                              const float* __restrict__ dinv,
                                              const float* __restrict__ b1,
                                              float* __restrict__ outp,
                                              int NBUCK, int N) {
    __shared__ float acc[BDIM * 17];
    int b = blockIdx.x;
    for (int i = threadIdx.x; i < BDIM * 17; i += 256) acc[i] = 0.0f;
    __syncthreads();
    const int j = threadIdx.x & 15;
    const int grp = threadIdx.x >> 4;  // 16 edge slots per block
    int beg = bbase[b], end = bbase[b + 1];
    int e = beg + grp;
    for (; e + 16 < end; e += 32) {
        float2 p0 = tmp[e];
        float2 p1 = tmp[e + 16];
        int w0 = __float_as_int(p0.x);
        int w1 = __float_as_int(p1.x);
        int s0 = w0 & 0xFFFFFF, s1 = w1 & 0xFFFFFF;
        int dl0 = ((unsigned)w0) >> 24, dl1 = ((unsigned)w1) >> 24;
        float m0 = dinv[s0] * p0.y;
        float m1 = dinv[s1] * p1.y;
        float f0 = feat[(size_t)s0 * 16 + j];
        float f1 = feat[(size_t)s1 * 16 + j];
        atomicAdd(&acc[dl0 * 17 + j], m0 * f0);
        atomicAdd(&acc[dl1 * 17 + j], m1 * f1);
    }
    if (e < end) {
        float2 p0 = tmp[e];
        int w0 = __float_as_int(p0.x);
        int s0 = w0 & 0xFFFFFF;
        int dl0 = ((unsigned)w0) >> 24;
        float m0 = dinv[s0] * p0.y;
        atomicAdd(&acc[dl0 * 17 + j], m0 * feat[(size_t)s0 * 16 + j]);
    }
    __syncthreads();
    for (int i = threadIdx.x; i < BDIM * 16; i += 256) {
        int d = i >> 4, jj = i & 15;
        int node = (b << BSHIFT) + d;
        if (node < N) {
            float dn = dinv[node];
            float r = dn * acc[d * 17 + jj] + dn * dn * feat[(size_t)node * 16 + jj];
            if (LAYER == 1) r = fmaxf(r + b1[jj], 0.0f);
            outp[(size_t)node * 16 + jj] = r;
        }
    }
}

// t[N][16] = x[N][512] @ W1[512][16]; 16 lanes/row, each owns 8 float4 k-slices.
__global__ __launch_bounds__(256) void gemm1_kernel(const float* __restrict__ x,
                                                    const float* __restrict__ W1,
                                                    float* __restrict__ t, int N) {
    __shared__ float w1t[16 * 520];
    for (int idx = threadIdx.x; idx < D_IN * D_HID; idx += 256) {
        int k = idx >> 4, j = idx & 15;
        w1t[j * 520 + k] = W1[idx];
    }
    __syncthreads();

    const int wave = threadIdx.x >> 6;
    const int lane = threadIdx.x & 63;
    const int g = lane >> 4;
    const int s = lane & 15;

    for (int base = blockIdx.x * 16; base < N; base += gridDim.x * 16) {
        int row = base + wave * 4 + g;
        if (row < N) {
            const float4* xr = (const float4*)(x + (size_t)row * D_IN);
            float4 xv[8];
#pragma unroll
            for (int i = 0; i < 8; ++i) xv[i] = xr[s + 16 * i];
            float acc[16];
#pragma unroll
            for (int j = 0; j < 16; ++j) acc[j] = 0.0f;
#pragma unroll
            for (int i = 0; i < 8; ++i) {
                int kb = 4 * s + 64 * i;
#pragma unroll
                for (int j = 0; j < 16; ++j) {
                    const float4 wv = *(const float4*)&w1t[j * 520 + kb];
                    acc[j] += xv[i].x * wv.x + xv[i].y * wv.y + xv[i].z * wv.z + xv[i].w * wv.w;
                }
            }
#pragma unroll
            for (int j = 0; j < 16; ++j) {
#pragma unroll
                for (int m = 1; m < 16; m <<= 1) acc[j] += __shfl_xor(acc[j], m, 64);
            }
            float v = acc[0];
#pragma unroll
            for (int j = 1; j < 16; ++j) v = (s == j) ? acc[j] : v;
            t[(size_t)row * 16 + s] = v;
        }
    }
}

// out[node][c] = log_softmax( v[node] @ W2 + b2 ); one wave per node.
__global__ __launch_bounds__(256) void out_kernel(const float* __restrict__ v,
                                                  const float* __restrict__ W2,
                                                  const float* __restrict__ b2,
                                                  float* __restrict__ out, int N) {
    __shared__ float w2s[16 * 64];
    __shared__ float b2s[64];
    for (int idx = threadIdx.x; idx < 16 * 64; idx += 256) w2s[idx] = W2[idx];
    if (threadIdx.x < 64) b2s[threadIdx.x] = b2[threadIdx.x];
    __syncthreads();

    const int wave = threadIdx.x >> 6;
    const int lane = threadIdx.x & 63;

    for (int node = blockIdx.x * 4 + wave; node < N; node += gridDim.x * 4) {
        const float4* v4 = (const float4*)(v + (size_t)node * 16);
        float z = b2s[lane];
#pragma unroll
        for (int q = 0; q < 4; ++q) {
            float4 a = v4[q];
            z += a.x * w2s[(4 * q + 0) * 64 + lane];
            z += a.y * w2s[(4 * q + 1) * 64 + lane];
            z += a.z * w2s[(4 * q + 2) * 64 + lane];
            z += a.w * w2s[(4 * q + 3) * 64 + lane];
        }
        float m = z;
#pragma unroll
        for (int off = 32; off; off >>= 1) m = fmaxf(m, __shfl_xor(m, off, 64));
        float ez = __expf(z - m);
        float ssum = ez;
#pragma unroll
        for (int off = 32; off; off >>= 1) ssum += __shfl_xor(ssum, off, 64);
        out[(size_t)node * 64 + lane] = z - m - __logf(ssum);
    }
}

extern "C" void kernel_launch(void* const* d_in, const int* in_sizes, int n_in,
                              void* d_out, int out_size, void* d_ws, size_t ws_size,
                              hipStream_t stream) {
    const float* x  = (const float*)d_in[0];
    const int*   ei = (const int*)d_in[1];
    const float* ew = (const float*)d_in[2];
    const float* W1 = (const float*)d_in[3];
    const float* b1 = (const float*)d_in[4];
    const float* W2 = (const float*)d_in[5];
    const float* b2 = (const float*)d_in[6];
    float* out = (float*)d_out;

    const int N = in_sizes[0] / D_IN;
    const int E = in_sizes[2];
    const int* srcI = ei;
    const int* dstI = ei + E;

    const int NBUCK = (N + BDIM - 1) >> BSHIFT;    // 782 for N=100K (needs <=1024)
    const int chunk = (E + NBLK0 - 1) / NBLK0;

    // ws layout (float units, offsets padded to 4):
    // dinv[N] bbase[NBUCK+1] btot[NBUCK] bcnt[NBLK0*NBUCK] t[16N] h1[16N] tmp[2E]
    float* ws = (float*)d_ws;
    size_t o = 0;
    float* dinv   = ws + o;               o += (size_t)N;            o = (o + 3) & ~(size_t)3;
    int*   bbase  = (int*)(ws + o);       o += (size_t)NBUCK + 1;    o = (o + 3) & ~(size_t)3;
    int*   btot   = (int*)(ws + o);       o += (size_t)NBUCK;        o = (o + 3) & ~(size_t)3;
    int*   bcnt   = (int*)(ws + o);       o += (size_t)NBLK0 * NBUCK; o = (o + 3) & ~(size_t)3;
    float* t      = ws + o;               o += (size_t)16 * N;       o = (o + 3) & ~(size_t)3;
    float* h1     = ws + o;               o += (size_t)16 * N;       o = (o + 3) & ~(size_t)3;
    float2* tmp   = (float2*)(ws + o);
    float* v = t;  // layer-2 output reuses t (t dead after agg layer 1)

    p0_count<<<NBLK0, 256, NBUCK * sizeof(int), stream>>>(dstI, bcnt, NBUCK, E, chunk);
    p_scan1<<<NBUCK, 256, 0, stream>>>(bcnt, btot, NBUCK);
    p_scan2<<<1, 1024, 0, stream>>>(btot, bbase, NBUCK, E);
    p1_scatter<<<NBLK0, 256, NBUCK * sizeof(int), stream>>>(srcI, dstI, ew, bcnt, bbase,
                                                            tmp, NBUCK, E, chunk);
    p2_dinv<<<NBUCK, 256, 0, stream>>>(tmp, bbase, dinv, NBUCK, N);

    gemm1_kernel<<<1024, 256, 0, stream>>>(x, W1, t, N);

    p3_agg<1><<<NBUCK, 256, 0, stream>>>(tmp, bbase, t, dinv, b1, h1, NBUCK, N);
    p3_agg<2><<<NBUCK, 256, 0, stream>>>(tmp, bbase, h1, dinv, b1, v, NBUCK, N);

    out_kernel<<<2048, 256, 0, stream>>>(v, W2, b2, out, N);
}

// Round 3
// 657.861 us; speedup vs baseline: 1.7068x; 1.7068x over previous
//
#include <hip/hip_runtime.h>
#include <hip/hip_bf16.h>

// GCN, round-6: hybrid of round-4 (fast pull-based CSR aggregation) and
// round-5 (global-atomic-free LDS bucketing).
//  - front-end: p0 bucket histogram -> 2 scans -> p1 bucket scatter (all LDS
//    atomics; round-4's hist/scatter global atomics were memory-side RMWs)
//  - NEW p4_sort: per 128-node bucket, LDS counting sort -> full CSR order
//    (row_start) + fused dinv computation. Zero global atomics.
//  - back-end: round-4's proven one-wave-per-node pull agg + gemm1 + out.
//    (round-5's push agg with LDS accumulators was latency-bound: 341us,
//    VALUBusy 4.8%, 782 blocks -> reverted)
//  - memory: sorted[2E] aliases d_out (dead until out_kernel, exactly N*64
//    floats = 2E here); t/h1 alias tmp (dead after p4_sort). ws use ~28MB.

#define D_IN 512
#define D_HID 16
#define D_OUT 64
#define BDIM 128     // nodes per bucket
#define BSHIFT 7
#define NBLK0 512    // edge-chunk blocks for p0/p1 (p_scan1 assumes 512 = 2*256)

// ---------------- pass 0: per-chunk bucket histogram (LDS atomics) --------
__global__ __launch_bounds__(256) void p0_count(const int* __restrict__ dst,
                                                int* __restrict__ bcnt,
                                                int NBUCK, int E, int chunk) {
    extern __shared__ int hist[];  // NBUCK ints
    int k = blockIdx.x;
    for (int i = threadIdx.x; i < NBUCK; i += 256) hist[i] = 0;
    __syncthreads();
    int beg = k * chunk, end = min(beg + chunk, E);
    for (int e = beg + threadIdx.x; e < end; e += 256)
        atomicAdd(&hist[dst[e] >> BSHIFT], 1);
    __syncthreads();
    for (int i = threadIdx.x; i < NBUCK; i += 256)
        bcnt[(size_t)k * NBUCK + i] = hist[i];  // row-major by chunk: coalesced
}

// ------- scan 1: per bucket, exclusive scan over the NBLK0 chunks ---------
__global__ __launch_bounds__(256) void p_scan1(int* __restrict__ bcnt,
                                               int* __restrict__ btot, int NBUCK) {
    __shared__ int s[256];
    int b = blockIdx.x, t = threadIdx.x;
    int v0 = bcnt[(size_t)(2 * t) * NBUCK + b];
    int v1 = bcnt[(size_t)(2 * t + 1) * NBUCK + b];
    int pair = v0 + v1;
    s[t] = pair;
    __syncthreads();
    for (int off = 1; off < 256; off <<= 1) {
        int v = (t >= off) ? s[t - off] : 0;
        __syncthreads();
        s[t] += v;
        __syncthreads();
    }
    int ex = s[t] - pair;
    bcnt[(size_t)(2 * t) * NBUCK + b] = ex;
    bcnt[(size_t)(2 * t + 1) * NBUCK + b] = ex + v0;
    if (t == 255) btot[b] = s[255];
}

// ------- scan 2: exclusive scan of bucket totals -> bbase[NBUCK+1] --------
__global__ __launch_bounds__(1024) void p_scan2(const int* __restrict__ btot,
                                                int* __restrict__ bbase,
                                                int NBUCK, int E) {
    __shared__ int s[1024];
    int t = threadIdx.x;
    int v = (t < NBUCK) ? btot[t] : 0;
    s[t] = v;
    __syncthreads();
    for (int off = 1; off < 1024; off <<= 1) {
        int u = (t >= off) ? s[t - off] : 0;
        __syncthreads();
        s[t] += u;
        __syncthreads();
    }
    if (t < NBUCK) bbase[t] = s[t] - v;
    if (t == 0) bbase[NBUCK] = E;
}

// ---------------- pass 1: scatter into bucket-grouped COO -----------------
__global__ __launch_bounds__(256) void p1_scatter(const int* __restrict__ src,
                                                  const int* __restrict__ dst,
                                                  const float* __restrict__ w,
                                                  const int* __restrict__ bcnt,
                                                  const int* __restrict__ bbase,
                                                  float2* __restrict__ tmp,
                                                  int NBUCK, int E, int chunk) {
    extern __shared__ int cur[];  // NBUCK ints
    int k = blockIdx.x;
    for (int i = threadIdx.x; i < NBUCK; i += 256)
        cur[i] = bbase[i] + bcnt[(size_t)k * NBUCK + i];
    __syncthreads();
    int beg = k * chunk, end = min(beg + chunk, E);
    for (int e = beg + threadIdx.x; e < end; e += 256) {
        int d = dst[e];
        int b = d >> BSHIFT;
        int pos = atomicAdd(&cur[b], 1);
        tmp[pos] = make_float2(__int_as_float(((d & (BDIM - 1)) << 24) | src[e]), w[e]);
    }
}

// -------- pass 4: per-bucket LDS counting sort -> CSR; fused dinv ---------
// pass A: count per-node + accumulate weight degree (LDS atomics)
// scan 128 counters; write row_start + dinv; pass B: scatter to sorted.
__global__ __launch_bounds__(256) void p4_sort(const float2* __restrict__ tmp,
                                               const int* __restrict__ bbase,
                                               float2* __restrict__ sorted,
                                               int* __restrict__ row_start,
                                               float* __restrict__ dinv,
                                               int NBUCK, int N, int E) {
    __shared__ int cnt[BDIM];
    __shared__ float wdeg[BDIM];
    __shared__ int pre[BDIM];
    __shared__ int cur[BDIM];
    int b = blockIdx.x;
    if (threadIdx.x < BDIM) { cnt[threadIdx.x] = 0; wdeg[threadIdx.x] = 0.0f; }
    __syncthreads();
    int beg = bbase[b], end = bbase[b + 1];
    for (int e = beg + threadIdx.x; e < end; e += 256) {
        float2 p = tmp[e];
        int dl = ((unsigned)__float_as_int(p.x)) >> 24;
        atomicAdd(&cnt[dl], 1);
        atomicAdd(&wdeg[dl], p.y);
    }
    __syncthreads();
    if (threadIdx.x < BDIM) pre[threadIdx.x] = cnt[threadIdx.x];
    __syncthreads();
    for (int off = 1; off < BDIM; off <<= 1) {
        int add = 0;
        if (threadIdx.x < BDIM && threadIdx.x >= off) add = pre[threadIdx.x - off];
        __syncthreads();
        if (threadIdx.x < BDIM) pre[threadIdx.x] += add;
        __syncthreads();
    }
    if (threadIdx.x < BDIM) {
        int ex = beg + pre[threadIdx.x] - cnt[threadIdx.x];  // exclusive
        cur[threadIdx.x] = ex;
        int node = (b << BSHIFT) + threadIdx.x;
        if (node < N) {
            row_start[node] = ex;
            dinv[node] = __frsqrt_rn(1.0f + wdeg[threadIdx.x]);
        }
    }
    if (b == NBUCK - 1 && threadIdx.x == 0) row_start[N] = E;
    __syncthreads();
    for (int e = beg + threadIdx.x; e < end; e += 256) {
        float2 p = tmp[e];
        unsigned u = (unsigned)__float_as_int(p.x);
        int dl = u >> 24;
        int pos = atomicAdd(&cur[dl], 1);
        sorted[pos] = make_float2(__int_as_float((int)(u & 0xFFFFFFu)), p.y);
    }
}

// t[N][16] = x[N][512] @ W1[512][16]; 16 lanes/row, each owns 8 float4 k-slices.
__global__ __launch_bounds__(256) void gemm1_kernel(const float* __restrict__ x,
                                                    const float* __restrict__ W1,
                                                    float* __restrict__ t, int N) {
    __shared__ float w1t[16 * 520];
    for (int idx = threadIdx.x; idx < D_IN * D_HID; idx += 256) {
        int k = idx >> 4, j = idx & 15;
        w1t[j * 520 + k] = W1[idx];
    }
    __syncthreads();

    const int wave = threadIdx.x >> 6;
    const int lane = threadIdx.x & 63;
    const int g = lane >> 4;
    const int s = lane & 15;

    for (int base = blockIdx.x * 16; base < N; base += gridDim.x * 16) {
        int row = base + wave * 4 + g;
        if (row < N) {
            const float4* xr = (const float4*)(x + (size_t)row * D_IN);
            float4 xv[8];
#pragma unroll
            for (int i = 0; i < 8; ++i) xv[i] = xr[s + 16 * i];
            float acc[16];
#pragma unroll
            for (int j = 0; j < 16; ++j) acc[j] = 0.0f;
#pragma unroll
            for (int i = 0; i < 8; ++i) {
                int kb = 4 * s + 64 * i;
#pragma unroll
                for (int j = 0; j < 16; ++j) {
                    const float4 wv = *(const float4*)&w1t[j * 520 + kb];
                    acc[j] += xv[i].x * wv.x + xv[i].y * wv.y + xv[i].z * wv.z + xv[i].w * wv.w;
                }
            }
#pragma unroll
            for (int j = 0; j < 16; ++j) {
#pragma unroll
                for (int m = 1; m < 16; m <<= 1) acc[j] += __shfl_xor(acc[j], m, 64);
            }
            float v = acc[0];
#pragma unroll
            for (int j = 1; j < 16; ++j) v = (s == j) ? acc[j] : v;
            t[(size_t)row * 16 + s] = v;
        }
    }
}

// One wave per node, lane = k*16 + j (k = edge slice, j = feature dim).
template <int LAYER>
__global__ __launch_bounds__(256) void agg_kernel(const float2* __restrict__ sorted,
                                                  const int* __restrict__ row_start,
                                                  const float* __restrict__ feat,
                                                  const float* __restrict__ selfv,
                                                  const float* __restrict__ dinv,
                                                  const float* __restrict__ b1,
                                                  float* __restrict__ outp, int N) {
    int node = blockIdx.x * 4 + (threadIdx.x >> 6);
    if (node >= N) return;
    int lane = threadIdx.x & 63;
    int j = lane & 15, k = lane >> 4;
    int beg = row_start[node], end = row_start[node + 1];
    float acc = 0.0f;
    for (int e = beg + k; e < end; e += 4) {
        float2 p = sorted[e];
        int s = __float_as_int(p.x);
        acc += dinv[s] * p.y * feat[(size_t)s * 16 + j];
    }
    acc += __shfl_xor(acc, 16, 64);
    acc += __shfl_xor(acc, 32, 64);
    float dn = dinv[node];
    float sv = selfv[(size_t)node * 16 + j];
    float r = dn * acc + dn * dn * sv;
    if (LAYER == 1) r = fmaxf(r + b1[j], 0.0f);
    if (k == 0) outp[(size_t)node * 16 + j] = r;
}

// out[node][c] = log_softmax( v[node] @ W2 + b2 ); one wave per node.
__global__ __launch_bounds__(256) void out_kernel(const float* __restrict__ v,
                                                  const float* __restrict__ W2,
                                                  const float* __restrict__ b2,
                                                  float* __restrict__ out, int N) {
    __shared__ float w2s[16 * 64];
    __shared__ float b2s[64];
    for (int idx = threadIdx.x; idx < 16 * 64; idx += 256) w2s[idx] = W2[idx];
    if (threadIdx.x < 64) b2s[threadIdx.x] = b2[threadIdx.x];
    __syncthreads();

    const int wave = threadIdx.x >> 6;
    const int lane = threadIdx.x & 63;

    for (int node = blockIdx.x * 4 + wave; node < N; node += gridDim.x * 4) {
        const float4* v4 = (const float4*)(v + (size_t)node * 16);
        float z = b2s[lane];
#pragma unroll
        for (int q = 0; q < 4; ++q) {
            float4 a = v4[q];
            z += a.x * w2s[(4 * q + 0) * 64 + lane];
            z += a.y * w2s[(4 * q + 1) * 64 + lane];
            z += a.z * w2s[(4 * q + 2) * 64 + lane];
            z += a.w * w2s[(4 * q + 3) * 64 + lane];
        }
        float m = z;
#pragma unroll
        for (int off = 32; off; off >>= 1) m = fmaxf(m, __shfl_xor(m, off, 64));
        float ez = __expf(z - m);
        float ssum = ez;
#pragma unroll
        for (int off = 32; off; off >>= 1) ssum += __shfl_xor(ssum, off, 64);
        out[(size_t)node * 64 + lane] = z - m - __logf(ssum);
    }
}

extern "C" void kernel_launch(void* const* d_in, const int* in_sizes, int n_in,
                              void* d_out, int out_size, void* d_ws, size_t ws_size,
                              hipStream_t stream) {
    const float* x  = (const float*)d_in[0];
    const int*   ei = (const int*)d_in[1];
    const float* ew = (const float*)d_in[2];
    const float* W1 = (const float*)d_in[3];
    const float* b1 = (const float*)d_in[4];
    const float* W2 = (const float*)d_in[5];
    const float* b2 = (const float*)d_in[6];
    float* out = (float*)d_out;

    const int N = in_sizes[0] / D_IN;
    const int E = in_sizes[2];
    const int* srcI = ei;
    const int* dstI = ei + E;

    const int NBUCK = (N + BDIM - 1) >> BSHIFT;    // 782 for N=100K (needs <=1024)
    const int chunk = (E + NBLK0 - 1) / NBLK0;

    // ws layout (float units, offsets padded to 4):
    // dinv[N] row_start[N+2] bbase[NBUCK+1] btot[NBUCK] bcnt[NBLK0*NBUCK]
    // tmpRegion[max(2E,32N)]  (tmp, later t+h1)
    float* ws = (float*)d_ws;
    size_t o = 0;
    float* dinv      = ws + o;         o += (size_t)N;             o = (o + 3) & ~(size_t)3;
    int*   row_start = (int*)(ws + o); o += (size_t)N + 2;         o = (o + 3) & ~(size_t)3;
    int*   bbase     = (int*)(ws + o); o += (size_t)NBUCK + 1;     o = (o + 3) & ~(size_t)3;
    int*   btot      = (int*)(ws + o); o += (size_t)NBUCK;         o = (o + 3) & ~(size_t)3;
    int*   bcnt      = (int*)(ws + o); o += (size_t)NBLK0 * NBUCK; o = (o + 3) & ~(size_t)3;
    float* tmpR      = ws + o;
    size_t tmpsz = (size_t)2 * E; if ((size_t)32 * N > tmpsz) tmpsz = (size_t)32 * N;
    o += tmpsz;                                                    o = (o + 3) & ~(size_t)3;

    float2* tmp = (float2*)tmpR;       // bucket-grouped COO; dead after p4_sort
    float*  t   = tmpR;                // gemm1 output (aliases tmp)
    float*  h1  = tmpR + (size_t)16 * N;
    float*  v   = t;                   // layer-2 output reuses t

    // sorted[2E] aliases d_out (N*64 floats = 2E here); dead before out_kernel
    float2* sorted = ((size_t)out_size >= (size_t)E * 8)
                         ? (float2*)d_out
                         : (float2*)(ws + o);

    p0_count<<<NBLK0, 256, NBUCK * sizeof(int), stream>>>(dstI, bcnt, NBUCK, E, chunk);
    p_scan1<<<NBUCK, 256, 0, stream>>>(bcnt, btot, NBUCK);
    p_scan2<<<1, 1024, 0, stream>>>(btot, bbase, NBUCK, E);
    p1_scatter<<<NBLK0, 256, NBUCK * sizeof(int), stream>>>(srcI, dstI, ew, bcnt, bbase,
                                                            tmp, NBUCK, E, chunk);
    p4_sort<<<NBUCK, 256, 0, stream>>>(tmp, bbase, sorted, row_start, dinv, NBUCK, N, E);

    gemm1_kernel<<<1024, 256, 0, stream>>>(x, W1, t, N);

    agg_kernel<1><<<(N + 3) / 4, 256, 0, stream>>>(sorted, row_start, t, t, dinv, b1, h1, N);
    agg_kernel<2><<<(N + 3) / 4, 256, 0, stream>>>(sorted, row_start, h1, h1, dinv, b1, v, N);

    out_kernel<<<2048, 256, 0, stream>>>(v, W2, b2, out, N);
}

// Round 4
// 631.699 us; speedup vs baseline: 1.7775x; 1.0414x over previous
//
#include <hip/hip_runtime.h>
#include <hip/hip_bf16.h>

// GCN, round-7. Changes vs round-6 (657us):
//  - top dispatch is now the HARNESS's 800MB workspace zero-fill (~120us,
//    fixed): every kernel of ours is <118us. Residual budget says the two
//    agg layers (~250-300us combined) dominate: latency-bound 2-deep
//    dependent-gather chain (sorted[e] -> dinv[s] -> feat[s]) at 4-way ILP.
//  - p4 split: p4a (count+wdeg -> row_start,dinv) + p4b (scatter storing
//    fully-normalized weight nw = w*dinv[s]*dinv[d]). The random dinv[s]
//    gather is paid once in p4b instead of in BOTH agg layers, and agg's
//    per-record chain shrinks to a single dependent feat gather.
//  - agg: paired float4 record loads -> 8 edges in flight per wave (was 4).
//  - out_kernel fused into agg<2> epilogue (shuffle-broadcast r_j, 16x64
//    W2 in LDS, in-wave log-softmax). sorted moved to ws (it aliased d_out,
//    which the fused kernel now writes while reading sorted).

#define D_IN 512
#define D_HID 16
#define D_OUT 64
#define BDIM 128     // nodes per bucket
#define BSHIFT 7
#define NBLK0 512    // edge-chunk blocks for p0/p1 (p_scan1 assumes 512 = 2*256)

// ---------------- pass 0: per-chunk bucket histogram (LDS atomics) --------
__global__ __launch_bounds__(256) void p0_count(const int* __restrict__ dst,
                                                int* __restrict__ bcnt,
                                                int NBUCK, int E, int chunk) {
    extern __shared__ int hist[];  // NBUCK ints
    int k = blockIdx.x;
    for (int i = threadIdx.x; i < NBUCK; i += 256) hist[i] = 0;
    __syncthreads();
    int beg = k * chunk, end = min(beg + chunk, E);
    for (int e = beg + threadIdx.x; e < end; e += 256)
        atomicAdd(&hist[dst[e] >> BSHIFT], 1);
    __syncthreads();
    for (int i = threadIdx.x; i < NBUCK; i += 256)
        bcnt[(size_t)k * NBUCK + i] = hist[i];  // row-major by chunk: coalesced
}

// ------- scan 1: per bucket, exclusive scan over the NBLK0 chunks ---------
__global__ __launch_bounds__(256) void p_scan1(int* __restrict__ bcnt,
                                               int* __restrict__ btot, int NBUCK) {
    __shared__ int s[256];
    int b = blockIdx.x, t = threadIdx.x;
    int v0 = bcnt[(size_t)(2 * t) * NBUCK + b];
    int v1 = bcnt[(size_t)(2 * t + 1) * NBUCK + b];
    int pair = v0 + v1;
    s[t] = pair;
    __syncthreads();
    for (int off = 1; off < 256; off <<= 1) {
        int v = (t >= off) ? s[t - off] : 0;
        __syncthreads();
        s[t] += v;
        __syncthreads();
    }
    int ex = s[t] - pair;
    bcnt[(size_t)(2 * t) * NBUCK + b] = ex;
    bcnt[(size_t)(2 * t + 1) * NBUCK + b] = ex + v0;
    if (t == 255) btot[b] = s[255];
}

// ------- scan 2: exclusive scan of bucket totals -> bbase[NBUCK+1] --------
__global__ __launch_bounds__(1024) void p_scan2(const int* __restrict__ btot,
                                                int* __restrict__ bbase,
                                                int NBUCK, int E) {
    __shared__ int s[1024];
    int t = threadIdx.x;
    int v = (t < NBUCK) ? btot[t] : 0;
    s[t] = v;
    __syncthreads();
    for (int off = 1; off < 1024; off <<= 1) {
        int u = (t >= off) ? s[t - off] : 0;
        __syncthreads();
        s[t] += u;
        __syncthreads();
    }
    if (t < NBUCK) bbase[t] = s[t] - v;
    if (t == 0) bbase[NBUCK] = E;
}

// ---------------- pass 1: scatter into bucket-grouped COO -----------------
__global__ __launch_bounds__(256) void p1_scatter(const int* __restrict__ src,
                                                  const int* __restrict__ dst,
                                                  const float* __restrict__ w,
                                                  const int* __restrict__ bcnt,
                                                  const int* __restrict__ bbase,
                                                  float2* __restrict__ tmp,
                                                  int NBUCK, int E, int chunk) {
    extern __shared__ int cur[];  // NBUCK ints
    int k = blockIdx.x;
    for (int i = threadIdx.x; i < NBUCK; i += 256)
        cur[i] = bbase[i] + bcnt[(size_t)k * NBUCK + i];
    __syncthreads();
    int beg = k * chunk, end = min(beg + chunk, E);
    for (int e = beg + threadIdx.x; e < end; e += 256) {
        int d = dst[e];
        int b = d >> BSHIFT;
        int pos = atomicAdd(&cur[b], 1);
        tmp[pos] = make_float2(__int_as_float(((d & (BDIM - 1)) << 24) | src[e]), w[e]);
    }
}

// -------- pass 4a: per-bucket count + wdeg -> row_start, dinv -------------
__global__ __launch_bounds__(256) void p4a_count(const float2* __restrict__ tmp,
                                                 const int* __restrict__ bbase,
                                                 int* __restrict__ row_start,
                                                 float* __restrict__ dinv,
                                                 int NBUCK, int N, int E) {
    __shared__ int cnt[BDIM];
    __shared__ float wdeg[BDIM];
    __shared__ int pre[BDIM];
    int b = blockIdx.x;
    if (threadIdx.x < BDIM) { cnt[threadIdx.x] = 0; wdeg[threadIdx.x] = 0.0f; }
    __syncthreads();
    int beg = bbase[b], end = bbase[b + 1];
    for (int e = beg + threadIdx.x; e < end; e += 256) {
        float2 p = tmp[e];
        int dl = ((unsigned)__float_as_int(p.x)) >> 24;
        atomicAdd(&cnt[dl], 1);
        atomicAdd(&wdeg[dl], p.y);
    }
    __syncthreads();
    if (threadIdx.x < BDIM) pre[threadIdx.x] = cnt[threadIdx.x];
    __syncthreads();
    for (int off = 1; off < BDIM; off <<= 1) {
        int add = 0;
        if (threadIdx.x < BDIM && threadIdx.x >= off) add = pre[threadIdx.x - off];
        __syncthreads();
        if (threadIdx.x < BDIM) pre[threadIdx.x] += add;
        __syncthreads();
    }
    if (threadIdx.x < BDIM) {
        int node = (b << BSHIFT) + threadIdx.x;
        if (node < N) {
            row_start[node] = beg + pre[threadIdx.x] - cnt[threadIdx.x];  // exclusive
            dinv[node] = __frsqrt_rn(1.0f + wdeg[threadIdx.x]);
        }
    }
    if (b == NBUCK - 1 && threadIdx.x == 0) row_start[N] = E;
}

// -------- pass 4b: scatter to CSR with fully-normalized weight ------------
__global__ __launch_bounds__(256) void p4b_scatter(const float2* __restrict__ tmp,
                                                   const int* __restrict__ bbase,
                                                   const int* __restrict__ row_start,
                                                   const float* __restrict__ dinv,
                                                   float2* __restrict__ sorted, int N) {
    __shared__ int cur[BDIM];
    __shared__ float dl_dinv[BDIM];
    int b = blockIdx.x;
    if (threadIdx.x < BDIM) {
        int node = (b << BSHIFT) + threadIdx.x;
        cur[threadIdx.x] = (node < N) ? row_start[node] : 0;
        dl_dinv[threadIdx.x] = (node < N) ? dinv[node] : 0.0f;
    }
    __syncthreads();
    int beg = bbase[b], end = bbase[b + 1];
    for (int e = beg + threadIdx.x; e < end; e += 256) {
        float2 p = tmp[e];
        unsigned u = (unsigned)__float_as_int(p.x);
        int dl = u >> 24;
        int s = (int)(u & 0xFFFFFFu);
        int pos = atomicAdd(&cur[dl], 1);
        float nw = p.y * dinv[s] * dl_dinv[dl];
        sorted[pos] = make_float2(__int_as_float(s), nw);
    }
}

// t[N][16] = x[N][512] @ W1[512][16]; 16 lanes/row, each owns 8 float4 k-slices.
__global__ __launch_bounds__(256) void gemm1_kernel(const float* __restrict__ x,
                                                    const float* __restrict__ W1,
                                                    float* __restrict__ t, int N) {
    __shared__ float w1t[16 * 520];
    for (int idx = threadIdx.x; idx < D_IN * D_HID; idx += 256) {
        int k = idx >> 4, j = idx & 15;
        w1t[j * 520 + k] = W1[idx];
    }
    __syncthreads();

    const int wave = threadIdx.x >> 6;
    const int lane = threadIdx.x & 63;
    const int g = lane >> 4;
    const int s = lane & 15;

    for (int base = blockIdx.x * 16; base < N; base += gridDim.x * 16) {
        int row = base + wave * 4 + g;
        if (row < N) {
            const float4* xr = (const float4*)(x + (size_t)row * D_IN);
            float4 xv[8];
#pragma unroll
            for (int i = 0; i < 8; ++i) xv[i] = xr[s + 16 * i];
            float acc[16];
#pragma unroll
            for (int j = 0; j < 16; ++j) acc[j] = 0.0f;
#pragma unroll
            for (int i = 0; i < 8; ++i) {
                int kb = 4 * s + 64 * i;
#pragma unroll
                for (int j = 0; j < 16; ++j) {
                    const float4 wv = *(const float4*)&w1t[j * 520 + kb];
                    acc[j] += xv[i].x * wv.x + xv[i].y * wv.y + xv[i].z * wv.z + xv[i].w * wv.w;
                }
            }
#pragma unroll
            for (int j = 0; j < 16; ++j) {
#pragma unroll
                for (int m = 1; m < 16; m <<= 1) acc[j] += __shfl_xor(acc[j], m, 64);
            }
            float v = acc[0];
#pragma unroll
            for (int j = 1; j < 16; ++j) v = (s == j) ? acc[j] : v;
            t[(size_t)row * 16 + s] = v;
        }
    }
}

// One wave per node. Weights in sorted are pre-normalized (dinv[s]*w*dinv[d]).
// Paired float4 loads: 4 k-lanes x 2 records = 8 edges in flight per wave.
// LAYER==1: +b1, ReLU, write h1[node][16].
// LAYER==2: fused W2 matvec + log_softmax, write out[node][64].
template <int LAYER>
__global__ __launch_bounds__(256) void agg_kernel(const float2* __restrict__ sorted,
                                                  const int* __restrict__ row_start,
                                                  const float* __restrict__ feat,
                                                  const float* __restrict__ dinv,
                                                  const float* __restrict__ b1,
                                                  const float* __restrict__ W2,
                                                  const float* __restrict__ b2,
                                                  float* __restrict__ outp, int N) {
    __shared__ float w2s[16 * 64];
    __shared__ float b2s[64];
    if (LAYER == 2) {
        for (int idx = threadIdx.x; idx < 16 * 64; idx += 256) w2s[idx] = W2[idx];
        if (threadIdx.x < 64) b2s[threadIdx.x] = b2[threadIdx.x];
        __syncthreads();
    }
    int node = blockIdx.x * 4 + (threadIdx.x >> 6);
    if (node >= N) return;
    int lane = threadIdx.x & 63;
    int j = lane & 15, k = lane >> 4;
    int beg = row_start[node], end = row_start[node + 1];
    float acc = 0.0f;
    int i0 = beg;
    if ((i0 & 1) && i0 < end) {          // odd head record -> k==0
        if (k == 0) {
            float2 p = sorted[i0];
            acc += p.y * feat[(size_t)__float_as_int(p.x) * 16 + j];
        }
        ++i0;
    }
    for (int e = i0 + 2 * k; e + 1 < end; e += 8) {   // e even: 16B aligned
        float4 q = *(const float4*)(sorted + e);
        int s0 = __float_as_int(q.x);
        int s1 = __float_as_int(q.z);
        acc += q.y * feat[(size_t)s0 * 16 + j];
        acc += q.w * feat[(size_t)s1 * 16 + j];
    }
    if ((end > i0) && ((end - i0) & 1) && k == 0) {   // odd tail record
        float2 p = sorted[end - 1];
        acc += p.y * feat[(size_t)__float_as_int(p.x) * 16 + j];
    }
    acc += __shfl_xor(acc, 16, 64);
    acc += __shfl_xor(acc, 32, 64);      // all lanes now hold acc for their j
    float dn = dinv[node];
    float r = acc + dn * dn * feat[(size_t)node * 16 + j];  // self loop
    if (LAYER == 1) {
        r = fmaxf(r + b1[j], 0.0f);
        if (lane < 16) outp[(size_t)node * 16 + j] = r;
    } else {
        float z = b2s[lane];
#pragma unroll
        for (int j2 = 0; j2 < 16; ++j2)
            z += __shfl(r, j2, 64) * w2s[j2 * 64 + lane];
        float m = z;
#pragma unroll
        for (int off = 32; off; off >>= 1) m = fmaxf(m, __shfl_xor(m, off, 64));
        float ez = __expf(z - m);
        float ssum = ez;
#pragma unroll
        for (int off = 32; off; off >>= 1) ssum += __shfl_xor(ssum, off, 64);
        outp[(size_t)node * 64 + lane] = z - m - __logf(ssum);
    }
}

extern "C" void kernel_launch(void* const* d_in, const int* in_sizes, int n_in,
                              void* d_out, int out_size, void* d_ws, size_t ws_size,
                              hipStream_t stream) {
    const float* x  = (const float*)d_in[0];
    const int*   ei = (const int*)d_in[1];
    const float* ew = (const float*)d_in[2];
    const float* W1 = (const float*)d_in[3];
    const float* b1 = (const float*)d_in[4];
    const float* W2 = (const float*)d_in[5];
    const float* b2 = (const float*)d_in[6];
    float* out = (float*)d_out;

    const int N = in_sizes[0] / D_IN;
    const int E = in_sizes[2];
    const int* srcI = ei;
    const int* dstI = ei + E;

    const int NBUCK = (N + BDIM - 1) >> BSHIFT;    // 782 for N=100K (needs <=1024)
    const int chunk = (E + NBLK0 - 1) / NBLK0;

    // ws layout (float units, offsets padded to 4 = 16B):
    // dinv[N] row_start[N+2] bbase btot bcnt[NBLK0*NBUCK]
    // tmpR[max(2E,32N)] (tmp, later t+h1)  sorted[2E]
    float* ws = (float*)d_ws;
    size_t o = 0;
    float* dinv      = ws + o;         o += (size_t)N;             o = (o + 3) & ~(size_t)3;
    int*   row_start = (int*)(ws + o); o += (size_t)N + 2;         o = (o + 3) & ~(size_t)3;
    int*   bbase     = (int*)(ws + o); o += (size_t)NBUCK + 1;     o = (o + 3) & ~(size_t)3;
    int*   btot      = (int*)(ws + o); o += (size_t)NBUCK;         o = (o + 3) & ~(size_t)3;
    int*   bcnt      = (int*)(ws + o); o += (size_t)NBLK0 * NBUCK; o = (o + 3) & ~(size_t)3;
    float* tmpR      = ws + o;
    size_t tmpsz = (size_t)2 * E; if ((size_t)32 * N > tmpsz) tmpsz = (size_t)32 * N;
    o += tmpsz;                                                    o = (o + 3) & ~(size_t)3;
    float2* sorted   = (float2*)(ws + o);

    float2* tmp = (float2*)tmpR;       // bucket-grouped COO; dead after p4b
    float*  t   = tmpR;                // gemm1 output (aliases tmp)
    float*  h1  = tmpR + (size_t)16 * N;

    p0_count<<<NBLK0, 256, NBUCK * sizeof(int), stream>>>(dstI, bcnt, NBUCK, E, chunk);
    p_scan1<<<NBUCK, 256, 0, stream>>>(bcnt, btot, NBUCK);
    p_scan2<<<1, 1024, 0, stream>>>(btot, bbase, NBUCK, E);
    p1_scatter<<<NBLK0, 256, NBUCK * sizeof(int), stream>>>(srcI, dstI, ew, bcnt, bbase,
                                                            tmp, NBUCK, E, chunk);
    p4a_count<<<NBUCK, 256, 0, stream>>>(tmp, bbase, row_start, dinv, NBUCK, N, E);
    p4b_scatter<<<NBUCK, 256, 0, stream>>>(tmp, bbase, row_start, dinv, sorted, N);

    gemm1_kernel<<<1024, 256, 0, stream>>>(x, W1, t, N);

    agg_kernel<1><<<(N + 3) / 4, 256, 0, stream>>>(sorted, row_start, t, dinv,
                                                   b1, W2, b2, h1, N);
    agg_kernel<2><<<(N + 3) / 4, 256, 0, stream>>>(sorted, row_start, h1, dinv,
                                                   b1, W2, b2, out, N);
}

// Round 5
// 575.120 us; speedup vs baseline: 1.9523x; 1.0984x over previous
//
#include <hip/hip_runtime.h>
#include <hip/hip_bf16.h>

// GCN, round-8. Changes vs round-7 (631us):
//  - top-5 is all harness fill (~120us fixed); our kernels hide below it.
//    Two consistent cost decompositions (agg-heavy vs front-heavy) -> attack
//    both: agg lane remap (16 edge streams x float4 feature lanes = 32 edges
//    in flight/wave, chain depth 4x -> ~1x per node) + int4/float4-vectorized
//    edge reads in p0/p1/p4a/p4b (these run at <1% VALUBusy: issue-bound).
//  - gemm1 grid 1024 -> 2048.

#define D_IN 512
#define D_HID 16
#define D_OUT 64
#define BDIM 128     // nodes per bucket
#define BSHIFT 7
#define NBLK0 512    // edge-chunk blocks for p0/p1 (p_scan1 assumes 512 = 2*256)

// ---------------- pass 0: per-chunk bucket histogram (LDS atomics) --------
__global__ __launch_bounds__(256) void p0_count(const int* __restrict__ dst,
                                                int* __restrict__ bcnt,
                                                int NBUCK, int E, int chunk) {
    extern __shared__ int hist[];  // NBUCK ints
    int k = blockIdx.x;
    for (int i = threadIdx.x; i < NBUCK; i += 256) hist[i] = 0;
    __syncthreads();
    int beg = k * chunk, end = min(beg + chunk, E);   // beg multiple of 4
    int e = beg + threadIdx.x * 4;
    for (; e + 3 < end; e += 1024) {
        int4 d4 = *(const int4*)(dst + e);
        atomicAdd(&hist[d4.x >> BSHIFT], 1);
        atomicAdd(&hist[d4.y >> BSHIFT], 1);
        atomicAdd(&hist[d4.z >> BSHIFT], 1);
        atomicAdd(&hist[d4.w >> BSHIFT], 1);
    }
    for (int q = e; q < min(e + 4, end); ++q)          // partial quad tail
        atomicAdd(&hist[dst[q] >> BSHIFT], 1);
    __syncthreads();
    for (int i = threadIdx.x; i < NBUCK; i += 256)
        bcnt[(size_t)k * NBUCK + i] = hist[i];  // row-major by chunk: coalesced
}

// ------- scan 1: per bucket, exclusive scan over the NBLK0 chunks ---------
__global__ __launch_bounds__(256) void p_scan1(int* __restrict__ bcnt,
                                               int* __restrict__ btot, int NBUCK) {
    __shared__ int s[256];
    int b = blockIdx.x, t = threadIdx.x;
    int v0 = bcnt[(size_t)(2 * t) * NBUCK + b];
    int v1 = bcnt[(size_t)(2 * t + 1) * NBUCK + b];
    int pair = v0 + v1;
    s[t] = pair;
    __syncthreads();
    for (int off = 1; off < 256; off <<= 1) {
        int v = (t >= off) ? s[t - off] : 0;
        __syncthreads();
        s[t] += v;
        __syncthreads();
    }
    int ex = s[t] - pair;
    bcnt[(size_t)(2 * t) * NBUCK + b] = ex;
    bcnt[(size_t)(2 * t + 1) * NBUCK + b] = ex + v0;
    if (t == 255) btot[b] = s[255];
}

// ------- scan 2: exclusive scan of bucket totals -> bbase[NBUCK+1] --------
__global__ __launch_bounds__(1024) void p_scan2(const int* __restrict__ btot,
                                                int* __restrict__ bbase,
                                                int NBUCK, int E) {
    __shared__ int s[1024];
    int t = threadIdx.x;
    int v = (t < NBUCK) ? btot[t] : 0;
    s[t] = v;
    __syncthreads();
    for (int off = 1; off < 1024; off <<= 1) {
        int u = (t >= off) ? s[t - off] : 0;
        __syncthreads();
        s[t] += u;
        __syncthreads();
    }
    if (t < NBUCK) bbase[t] = s[t] - v;
    if (t == 0) bbase[NBUCK] = E;
}

// ---------------- pass 1: scatter into bucket-grouped COO -----------------
__global__ __launch_bounds__(256) void p1_scatter(const int* __restrict__ src,
                                                  const int* __restrict__ dst,
                                                  const float* __restrict__ w,
                                                  const int* __restrict__ bcnt,
                                                  const int* __restrict__ bbase,
                                                  float2* __restrict__ tmp,
                                                  int NBUCK, int E, int chunk) {
    extern __shared__ int cur[];  // NBUCK ints
    int k = blockIdx.x;
    for (int i = threadIdx.x; i < NBUCK; i += 256)
        cur[i] = bbase[i] + bcnt[(size_t)k * NBUCK + i];
    __syncthreads();
    int beg = k * chunk, end = min(beg + chunk, E);   // beg multiple of 4
    int e = beg + threadIdx.x * 4;
    for (; e + 3 < end; e += 1024) {
        int4   s4 = *(const int4*)(src + e);
        int4   d4 = *(const int4*)(dst + e);
        float4 w4 = *(const float4*)(w + e);
        int p0 = atomicAdd(&cur[d4.x >> BSHIFT], 1);
        tmp[p0] = make_float2(__int_as_float(((d4.x & (BDIM - 1)) << 24) | s4.x), w4.x);
        int p1 = atomicAdd(&cur[d4.y >> BSHIFT], 1);
        tmp[p1] = make_float2(__int_as_float(((d4.y & (BDIM - 1)) << 24) | s4.y), w4.y);
        int p2 = atomicAdd(&cur[d4.z >> BSHIFT], 1);
        tmp[p2] = make_float2(__int_as_float(((d4.z & (BDIM - 1)) << 24) | s4.z), w4.z);
        int p3 = atomicAdd(&cur[d4.w >> BSHIFT], 1);
        tmp[p3] = make_float2(__int_as_float(((d4.w & (BDIM - 1)) << 24) | s4.w), w4.w);
    }
    for (int q = e; q < min(e + 4, end); ++q) {
        int d = dst[q];
        int pos = atomicAdd(&cur[d >> BSHIFT], 1);
        tmp[pos] = make_float2(__int_as_float(((d & (BDIM - 1)) << 24) | src[q]), w[q]);
    }
}

// -------- pass 4a: per-bucket count + wdeg -> row_start, dinv -------------
__global__ __launch_bounds__(256) void p4a_count(const float2* __restrict__ tmp,
                                                 const int* __restrict__ bbase,
                                                 int* __restrict__ row_start,
                                                 float* __restrict__ dinv,
                                                 int NBUCK, int N, int E) {
    __shared__ int cnt[BDIM];
    __shared__ float wdeg[BDIM];
    __shared__ int pre[BDIM];
    int b = blockIdx.x;
    if (threadIdx.x < BDIM) { cnt[threadIdx.x] = 0; wdeg[threadIdx.x] = 0.0f; }
    __syncthreads();
    int beg = bbase[b], end = bbase[b + 1];
    int vbeg = beg + (beg & 1);
    if ((beg & 1) && beg < end && threadIdx.x == 0) {
        float2 p = tmp[beg];
        int dl = ((unsigned)__float_as_int(p.x)) >> 24;
        atomicAdd(&cnt[dl], 1);
        atomicAdd(&wdeg[dl], p.y);
    }
    for (int e = vbeg + 2 * threadIdx.x; e + 1 < end; e += 512) {
        float4 q = *(const float4*)(tmp + e);
        int dl0 = ((unsigned)__float_as_int(q.x)) >> 24;
        int dl1 = ((unsigned)__float_as_int(q.z)) >> 24;
        atomicAdd(&cnt[dl0], 1);
        atomicAdd(&wdeg[dl0], q.y);
        atomicAdd(&cnt[dl1], 1);
        atomicAdd(&wdeg[dl1], q.w);
    }
    if ((end > vbeg) && ((end - vbeg) & 1) && threadIdx.x == 0) {
        float2 p = tmp[end - 1];
        int dl = ((unsigned)__float_as_int(p.x)) >> 24;
        atomicAdd(&cnt[dl], 1);
        atomicAdd(&wdeg[dl], p.y);
    }
    __syncthreads();
    if (threadIdx.x < BDIM) pre[threadIdx.x] = cnt[threadIdx.x];
    __syncthreads();
    for (int off = 1; off < BDIM; off <<= 1) {
        int add = 0;
        if (threadIdx.x < BDIM && threadIdx.x >= off) add = pre[threadIdx.x - off];
        __syncthreads();
        if (threadIdx.x < BDIM) pre[threadIdx.x] += add;
        __syncthreads();
    }
    if (threadIdx.x < BDIM) {
        int node = (b << BSHIFT) + threadIdx.x;
        if (node < N) {
            row_start[node] = beg + pre[threadIdx.x] - cnt[threadIdx.x];  // exclusive
            dinv[node] = __frsqrt_rn(1.0f + wdeg[threadIdx.x]);
        }
    }
    if (b == NBUCK - 1 && threadIdx.x == 0) row_start[N] = E;
}

// -------- pass 4b: scatter to CSR with fully-normalized weight ------------
__global__ __launch_bounds__(256) void p4b_scatter(const float2* __restrict__ tmp,
                                                   const int* __restrict__ bbase,
                                                   const int* __restrict__ row_start,
                                                   const float* __restrict__ dinv,
                                                   float2* __restrict__ sorted, int N) {
    __shared__ int cur[BDIM];
    __shared__ float dl_dinv[BDIM];
    int b = blockIdx.x;
    if (threadIdx.x < BDIM) {
        int node = (b << BSHIFT) + threadIdx.x;
        cur[threadIdx.x] = (node < N) ? row_start[node] : 0;
        dl_dinv[threadIdx.x] = (node < N) ? dinv[node] : 0.0f;
    }
    __syncthreads();
    int beg = bbase[b], end = bbase[b + 1];
    int vbeg = beg + (beg & 1);
    if ((beg & 1) && beg < end && threadIdx.x == 0) {
        float2 p = tmp[beg];
        unsigned u = (unsigned)__float_as_int(p.x);
        int dl = u >> 24, s = (int)(u & 0xFFFFFFu);
        int pos = atomicAdd(&cur[dl], 1);
        sorted[pos] = make_float2(__int_as_float(s), p.y * dinv[s] * dl_dinv[dl]);
    }
    for (int e = vbeg + 2 * threadIdx.x; e + 1 < end; e += 512) {
        float4 q = *(const float4*)(tmp + e);
        unsigned u0 = (unsigned)__float_as_int(q.x);
        unsigned u1 = (unsigned)__float_as_int(q.z);
        int dl0 = u0 >> 24, s0 = (int)(u0 & 0xFFFFFFu);
        int dl1 = u1 >> 24, s1 = (int)(u1 & 0xFFFFFFu);
        int pos0 = atomicAdd(&cur[dl0], 1);
        sorted[pos0] = make_float2(__int_as_float(s0), q.y * dinv[s0] * dl_dinv[dl0]);
        int pos1 = atomicAdd(&cur[dl1], 1);
        sorted[pos1] = make_float2(__int_as_float(s1), q.w * dinv[s1] * dl_dinv[dl1]);
    }
    if ((end > vbeg) && ((end - vbeg) & 1) && threadIdx.x == 0) {
        float2 p = tmp[end - 1];
        unsigned u = (unsigned)__float_as_int(p.x);
        int dl = u >> 24, s = (int)(u & 0xFFFFFFu);
        int pos = atomicAdd(&cur[dl], 1);
        sorted[pos] = make_float2(__int_as_float(s), p.y * dinv[s] * dl_dinv[dl]);
    }
}

// t[N][16] = x[N][512] @ W1[512][16]; 16 lanes/row, each owns 8 float4 k-slices.
__global__ __launch_bounds__(256) void gemm1_kernel(const float* __restrict__ x,
                                                    const float* __restrict__ W1,
                                                    float* __restrict__ t, int N) {
    __shared__ float w1t[16 * 520];
    for (int idx = threadIdx.x; idx < D_IN * D_HID; idx += 256) {
        int k = idx >> 4, j = idx & 15;
        w1t[j * 520 + k] = W1[idx];
    }
    __syncthreads();

    const int wave = threadIdx.x >> 6;
    const int lane = threadIdx.x & 63;
    const int g = lane >> 4;
    const int s = lane & 15;

    for (int base = blockIdx.x * 16; base < N; base += gridDim.x * 16) {
        int row = base + wave * 4 + g;
        if (row < N) {
            const float4* xr = (const float4*)(x + (size_t)row * D_IN);
            float4 xv[8];
#pragma unroll
            for (int i = 0; i < 8; ++i) xv[i] = xr[s + 16 * i];
            float acc[16];
#pragma unroll
            for (int j = 0; j < 16; ++j) acc[j] = 0.0f;
#pragma unroll
            for (int i = 0; i < 8; ++i) {
                int kb = 4 * s + 64 * i;
#pragma unroll
                for (int j = 0; j < 16; ++j) {
                    const float4 wv = *(const float4*)&w1t[j * 520 + kb];
                    acc[j] += xv[i].x * wv.x + xv[i].y * wv.y + xv[i].z * wv.z + xv[i].w * wv.w;
                }
            }
#pragma unroll
            for (int j = 0; j < 16; ++j) {
#pragma unroll
                for (int m = 1; m < 16; m <<= 1) acc[j] += __shfl_xor(acc[j], m, 64);
            }
            float v = acc[0];
#pragma unroll
            for (int j = 1; j < 16; ++j) v = (s == j) ? acc[j] : v;
            t[(size_t)row * 16 + s] = v;
        }
    }
}

// One wave per node. sorted weights pre-normalized (dinv[s]*w); dinv[d]
// applied at the epilogue. Lane = k*4 + jq: 16 edge streams, each edge's
// 16-float feat row fetched by 4 lanes as float4 (one 64B line).
// Paired record loads -> 32 edges in flight per wave.
template <int LAYER>
__global__ __launch_bounds__(256) void agg_kernel(const float2* __restrict__ sorted,
                                                  const int* __restrict__ row_start,
                                                  const float* __restrict__ feat,
                                                  const float* __restrict__ dinv,
                                                  const float* __restrict__ b1,
                                                  const float* __restrict__ W2,
                                                  const float* __restrict__ b2,
                                                  float* __restrict__ outp, int N) {
    __shared__ float w2s[16 * 64];
    __shared__ float b2s[64];
    if (LAYER == 2) {
        for (int idx = threadIdx.x; idx < 16 * 64; idx += 256) w2s[idx] = W2[idx];
        if (threadIdx.x < 64) b2s[threadIdx.x] = b2[threadIdx.x];
        __syncthreads();
    }
    int node = blockIdx.x * 4 + (threadIdx.x >> 6);
    if (node >= N) return;
    const int lane = threadIdx.x & 63;
    const int jq = lane & 3;    // feature quad (4 floats)
    const int k = lane >> 2;    // edge stream 0..15
    const float4* feat4 = (const float4*)feat;
    int beg = row_start[node], end = row_start[node + 1];
    float ax = 0.f, ay = 0.f, az = 0.f, aw = 0.f;
    int i0 = beg;
    if ((i0 & 1) && i0 < end) {          // odd head record
        if (k == 0) {
            float2 p = sorted[i0];
            float4 f = feat4[(size_t)__float_as_int(p.x) * 4 + jq];
            ax += p.y * f.x; ay += p.y * f.y; az += p.y * f.z; aw += p.y * f.w;
        }
        ++i0;
    }
    for (int e = i0 + 2 * k; e + 1 < end; e += 32) {   // e even: 16B aligned
        float4 q = *(const float4*)(sorted + e);
        int s0 = __float_as_int(q.x);
        int s1 = __float_as_int(q.z);
        float4 f0 = feat4[(size_t)s0 * 4 + jq];
        float4 f1 = feat4[(size_t)s1 * 4 + jq];
        ax += q.y * f0.x + q.w * f1.x;
        ay += q.y * f0.y + q.w * f1.y;
        az += q.y * f0.z + q.w * f1.z;
        aw += q.y * f0.w + q.w * f1.w;
    }
    if ((end > i0) && ((end - i0) & 1) && k == 0) {    // odd tail record
        float2 p = sorted[end - 1];
        float4 f = feat4[(size_t)__float_as_int(p.x) * 4 + jq];
        ax += p.y * f.x; ay += p.y * f.y; az += p.y * f.z; aw += p.y * f.w;
    }
#pragma unroll
    for (int m = 4; m < 64; m <<= 1) {   // reduce over the 16 k-streams
        ax += __shfl_xor(ax, m, 64);
        ay += __shfl_xor(ay, m, 64);
        az += __shfl_xor(az, m, 64);
        aw += __shfl_xor(aw, m, 64);
    }
    float dn = dinv[node];
    float dnn = dn * dn;
    float4 fs = feat4[(size_t)node * 4 + jq];
    float rx = ax + dnn * fs.x;
    float ry = ay + dnn * fs.y;
    float rz = az + dnn * fs.z;
    float rw = aw + dnn * fs.w;
    if (LAYER == 1) {
        float4 bq = ((const float4*)b1)[jq];
        rx = fmaxf(rx + bq.x, 0.0f);
        ry = fmaxf(ry + bq.y, 0.0f);
        rz = fmaxf(rz + bq.z, 0.0f);
        rw = fmaxf(rw + bq.w, 0.0f);
        if (k == 0) ((float4*)outp)[(size_t)node * 4 + jq] = make_float4(rx, ry, rz, rw);
    } else {
        float z = b2s[lane];
#pragma unroll
        for (int q2 = 0; q2 < 4; ++q2) {   // lane q2 holds quad q2 (k=0)
            float bx = __shfl(rx, q2, 64);
            float by = __shfl(ry, q2, 64);
            float bz = __shfl(rz, q2, 64);
            float bw = __shfl(rw, q2, 64);
            z += bx * w2s[(4 * q2 + 0) * 64 + lane] + by * w2s[(4 * q2 + 1) * 64 + lane]
               + bz * w2s[(4 * q2 + 2) * 64 + lane] + bw * w2s[(4 * q2 + 3) * 64 + lane];
        }
        float m = z;
#pragma unroll
        for (int off = 32; off; off >>= 1) m = fmaxf(m, __shfl_xor(m, off, 64));
        float ez = __expf(z - m);
        float ssum = ez;
#pragma unroll
        for (int off = 32; off; off >>= 1) ssum += __shfl_xor(ssum, off, 64);
        outp[(size_t)node * 64 + lane] = z - m - __logf(ssum);
    }
}

extern "C" void kernel_launch(void* const* d_in, const int* in_sizes, int n_in,
                              void* d_out, int out_size, void* d_ws, size_t ws_size,
                              hipStream_t stream) {
    const float* x  = (const float*)d_in[0];
    const int*   ei = (const int*)d_in[1];
    const float* ew = (const float*)d_in[2];
    const float* W1 = (const float*)d_in[3];
    const float* b1 = (const float*)d_in[4];
    const float* W2 = (const float*)d_in[5];
    const float* b2 = (const float*)d_in[6];
    float* out = (float*)d_out;

    const int N = in_sizes[0] / D_IN;
    const int E = in_sizes[2];
    const int* srcI = ei;
    const int* dstI = ei + E;

    const int NBUCK = (N + BDIM - 1) >> BSHIFT;    // 782 for N=100K (needs <=1024)
    const int chunk = (((E + NBLK0 - 1) / NBLK0) + 3) & ~3;  // mult of 4: int4 loads

    // ws layout (float units, offsets padded to 4 = 16B):
    float* ws = (float*)d_ws;
    size_t o = 0;
    float* dinv      = ws + o;         o += (size_t)N;             o = (o + 3) & ~(size_t)3;
    int*   row_start = (int*)(ws + o); o += (size_t)N + 2;         o = (o + 3) & ~(size_t)3;
    int*   bbase     = (int*)(ws + o); o += (size_t)NBUCK + 1;     o = (o + 3) & ~(size_t)3;
    int*   btot      = (int*)(ws + o); o += (size_t)NBUCK;         o = (o + 3) & ~(size_t)3;
    int*   bcnt      = (int*)(ws + o); o += (size_t)NBLK0 * NBUCK; o = (o + 3) & ~(size_t)3;
    float* tmpR      = ws + o;
    size_t tmpsz = (size_t)2 * E; if ((size_t)32 * N > tmpsz) tmpsz = (size_t)32 * N;
    o += tmpsz;                                                    o = (o + 3) & ~(size_t)3;
    float2* sorted   = (float2*)(ws + o);

    float2* tmp = (float2*)tmpR;       // bucket-grouped COO; dead after p4b
    float*  t   = tmpR;                // gemm1 output (aliases tmp)
    float*  h1  = tmpR + (size_t)16 * N;

    p0_count<<<NBLK0, 256, NBUCK * sizeof(int), stream>>>(dstI, bcnt, NBUCK, E, chunk);
    p_scan1<<<NBUCK, 256, 0, stream>>>(bcnt, btot, NBUCK);
    p_scan2<<<1, 1024, 0, stream>>>(btot, bbase, NBUCK, E);
    p1_scatter<<<NBLK0, 256, NBUCK * sizeof(int), stream>>>(srcI, dstI, ew, bcnt, bbase,
                                                            tmp, NBUCK, E, chunk);
    p4a_count<<<NBUCK, 256, 0, stream>>>(tmp, bbase, row_start, dinv, NBUCK, N, E);
    p4b_scatter<<<NBUCK, 256, 0, stream>>>(tmp, bbase, row_start, dinv, sorted, N);

    gemm1_kernel<<<2048, 256, 0, stream>>>(x, W1, t, N);

    agg_kernel<1><<<(N + 3) / 4, 256, 0, stream>>>(sorted, row_start, t, dinv,
                                                   b1, W2, b2, h1, N);
    agg_kernel<2><<<(N + 3) / 4, 256, 0, stream>>>(sorted, row_start, h1, dinv,
                                                   b1, W2, b2, out, N);
}